// Round 4
// baseline (158.355 us; speedup 1.0000x reference)
//
#include <hip/hip_runtime.h>

#define NN  50000
#define DEG 32
#define DF  128
#define DO  256
#define FEAT4 (NN * DF / 4)   // 1,600,000 float4 groups

typedef __bf16 bf16x8 __attribute__((ext_vector_type(8)));
typedef float  f32x4  __attribute__((ext_vector_type(4)));
typedef unsigned short u16x8 __attribute__((ext_vector_type(8)));

__device__ __forceinline__ unsigned short f2bf(float f) {
    unsigned u = __float_as_uint(f);
    u += 0x7FFF + ((u >> 16) & 1);     // round-to-nearest-even
    return (unsigned short)(u >> 16);
}
__device__ __forceinline__ float bf2f(unsigned short h) {
    return __uint_as_float(((unsigned)h) << 16);
}

// ---------------------------------------------------------------------------
// Convert: feat fp32 -> bf16 (vectorized), W fp32 [K][N] -> Wt bf16 [N][K].
// ---------------------------------------------------------------------------
__global__ __launch_bounds__(256) void convert_kernel(
    const float* __restrict__ feat, const float* __restrict__ W,
    unsigned short* __restrict__ featb, unsigned short* __restrict__ Wt)
{
    const int gid = blockIdx.x * 256 + threadIdx.x;
    if (gid < FEAT4) {
        const float4 v = ((const float4*)feat)[gid];
        ushort4 o;
        o.x = f2bf(v.x); o.y = f2bf(v.y); o.z = f2bf(v.z); o.w = f2bf(v.w);
        ((ushort4*)featb)[gid] = o;
    } else {
        const int t = gid - FEAT4;
        if (t < DO * DO) {
            const int n = t >> 8, k = t & 255;
            Wt[n * DO + k] = f2bf(W[k * DO + n]);   // write coalesced along k
        }
    }
}

// ---------------------------------------------------------------------------
// Sliced aggregation: feature dim split into 4 slices of 32 cols; the 3.2 MB
// table slice fits one XCD's 4 MiB L2. slice = (blockIdx&7)>>1 so, under the
// round-robin blockIdx->XCD heuristic, each XCD touches exactly one slice
// (perf-only assumption; correctness independent of mapping).
// Block: 64 nodes x 1 slice; thread = (node, 16B segment). Edges staged in
// LDS with stride 33 (bank = (node+d)%32 -> conflict-free broadcast reads).
// ---------------------------------------------------------------------------
#define ANODES 64
#define SFEAT  32

__global__ __launch_bounds__(256) void agg_kernel(
    const unsigned short* __restrict__ featb,
    const int*            __restrict__ edges,
    unsigned short*       __restrict__ aggb)
{
    const int slice = (blockIdx.x & 7) >> 1;
    const int nb    = ((blockIdx.x >> 3) << 1) | (blockIdx.x & 1);
    const int node0 = nb * ANODES;
    if (node0 >= NN) return;

    __shared__ int eds[ANODES * 33];

    for (int i = threadIdx.x; i < ANODES * DEG; i += 256) {
        const int nl = i >> 5, d = i & 31;
        int node = node0 + nl;
        if (node >= NN) node = NN - 1;
        eds[nl * 33 + d] = edges[node * DEG + d];
    }
    __syncthreads();

    const int nl  = threadIdx.x >> 2;      // 0..63 local node
    const int seg = threadIdx.x & 3;       // 16B segment of the 64B slice row
    const unsigned short* base = featb + slice * SFEAT + seg * 8;

    float a[8] = {0.f, 0.f, 0.f, 0.f, 0.f, 0.f, 0.f, 0.f};
    #pragma unroll
    for (int d = 0; d < DEG; ++d) {
        const int idx = eds[nl * 33 + d];
        const u16x8 v = *(const u16x8*)(base + (size_t)idx * DF);
        #pragma unroll
        for (int j = 0; j < 8; ++j) a[j] += bf2f(v[j]);
    }

    const int node = node0 + nl;
    if (node < NN) {
        const float s = 1.0f / (float)DEG;
        u16x8 o;
        #pragma unroll
        for (int j = 0; j < 8; ++j) o[j] = f2bf(a[j] * s);
        *(u16x8*)(aggb + (size_t)node * DF + slice * SFEAT + seg * 8) = o;
    }
}

// ---------------------------------------------------------------------------
// MFMA GEMM (R2 structure, known-good): out = relu([featb | aggb] @ Wt^T).
// 128x128 block tile, 4 waves 2x2, 16x16x32 bf16 MFMA, K staged via LDS.
// ---------------------------------------------------------------------------
#define BM  128
#define BN  128
#define LDA 72

__global__ __launch_bounds__(256) void gemm_kernel(
    const unsigned short* __restrict__ featb,
    const unsigned short* __restrict__ aggb,
    const unsigned short* __restrict__ Wt,
    float*                __restrict__ out)
{
    __shared__ __align__(16) unsigned short Asw[BM * LDA];
    __shared__ __align__(16) unsigned short Bsw[BN * LDA];

    const int tid  = threadIdx.x;
    const int m0   = blockIdx.x * BM;
    const int c0   = blockIdx.y * BN;
    const int wave = tid >> 6, lane = tid & 63;
    const int quad = lane >> 4, lr = lane & 15;
    const int wm   = (wave & 1) * 64;
    const int wn   = (wave >> 1) * 64;

    const int srow = tid >> 3;
    const int sseg = (tid & 7) * 8;

    f32x4 acc[4][4] = {};

    for (int kc = 0; kc < 4; ++kc) {
        const unsigned short* srcA = (kc < 2) ? (featb + kc * 64)
                                              : (aggb + (kc - 2) * 64);
        const unsigned short* srcB = Wt + kc * 64;

        __syncthreads();
        #pragma unroll
        for (int p = 0; p < 4; ++p) {
            const int r = p * 32 + srow;
            int node = m0 + r;
            if (node >= NN) node = NN - 1;
            const float4 va = *(const float4*)(srcA + (size_t)node * DF + sseg);
            *(float4*)(Asw + r * LDA + sseg) = va;
            const float4 vb = *(const float4*)(srcB + (size_t)(c0 + r) * DO + sseg);
            *(float4*)(Bsw + r * LDA + sseg) = vb;
        }
        __syncthreads();

        #pragma unroll
        for (int kk = 0; kk < 64; kk += 32) {
            bf16x8 af[4], bfr[4];
            #pragma unroll
            for (int i = 0; i < 4; ++i) {
                af[i]  = *(const bf16x8*)(Asw + (wm + i * 16 + lr) * LDA + kk + quad * 8);
                bfr[i] = *(const bf16x8*)(Bsw + (wn + i * 16 + lr) * LDA + kk + quad * 8);
            }
            #pragma unroll
            for (int mi = 0; mi < 4; ++mi)
                #pragma unroll
                for (int ni = 0; ni < 4; ++ni)
                    acc[mi][ni] = __builtin_amdgcn_mfma_f32_16x16x32_bf16(
                        af[mi], bfr[ni], acc[mi][ni], 0, 0, 0);
        }
    }

    #pragma unroll
    for (int mi = 0; mi < 4; ++mi) {
        #pragma unroll
        for (int r = 0; r < 4; ++r) {
            const int row = m0 + wm + mi * 16 + quad * 4 + r;
            if (row < NN) {
                #pragma unroll
                for (int ni = 0; ni < 4; ++ni) {
                    out[(size_t)row * DO + c0 + wn + ni * 16 + lr] =
                        fmaxf(acc[mi][ni][r], 0.f);
                }
            }
        }
    }
}

extern "C" void kernel_launch(void* const* d_in, const int* in_sizes, int n_in,
                              void* d_out, int out_size, void* d_ws, size_t ws_size,
                              hipStream_t stream)
{
    const float* feat  = (const float*)d_in[0];
    const int*   edges = (const int*)d_in[1];
    const float* W     = (const float*)d_in[2];
    float*       out   = (float*)d_out;

    unsigned short* aggb  = (unsigned short*)d_ws;            // 12.8 MB
    unsigned short* featb = aggb  + (size_t)NN * DF;          // 12.8 MB
    unsigned short* Wt    = featb + (size_t)NN * DF;          // 128 KB

    convert_kernel<<<(FEAT4 + DO * DO + 255) / 256, 256, 0, stream>>>(feat, W, featb, Wt);

    // 4 slices x 784 node-blocks, interleaved for XCD affinity: 8 * 392 blocks
    agg_kernel<<<8 * 392, 256, 0, stream>>>(featb, edges, aggb);

    dim3 grid((NN + BM - 1) / BM, DO / BN);
    gemm_kernel<<<grid, 256, 0, stream>>>(featb, aggb, Wt, out);
}

// Round 5
// 132.058 us; speedup vs baseline: 1.1991x; 1.1991x over previous
//
#include <hip/hip_runtime.h>

#define NN  50000
#define DEG 32
#define DF  128
#define DO  256
#define FEAT4 (NN * DF / 4)   // 1,600,000 float4 groups

typedef __bf16 bf16x8 __attribute__((ext_vector_type(8)));
typedef float  f32x4  __attribute__((ext_vector_type(4)));
typedef float  f32x2  __attribute__((ext_vector_type(2)));
typedef unsigned short u16x8 __attribute__((ext_vector_type(8)));

#if defined(__has_builtin)
#if __has_builtin(__builtin_amdgcn_cvt_pk_f32_fp8) && __has_builtin(__builtin_amdgcn_cvt_pk_fp8_f32)
#define HW_FP8 1
#endif
#endif
#ifndef HW_FP8
#define HW_FP8 0
#endif

__device__ __forceinline__ unsigned short f2bf(float f) {
    unsigned u = __float_as_uint(f);
    u += 0x7FFF + ((u >> 16) & 1);     // round-to-nearest-even
    return (unsigned short)(u >> 16);
}
__device__ __forceinline__ unsigned pkbf(float a, float b) {
    return (unsigned)f2bf(a) | ((unsigned)f2bf(b) << 16);
}

#if !HW_FP8
// fallback e4m3fn encode/decode (only if HW cvt builtins are unavailable)
__device__ __forceinline__ unsigned enc1_fp8(float f) {
    unsigned u = __float_as_uint(f);
    unsigned s = (u >> 31) << 7;
    float a = fabsf(f);
    if (!(a > 0.f)) return s;
    if (a >= 448.f) return s | 0x7E;
    u = __float_as_uint(a);
    int e = (int)((u >> 23) & 255) - 127;
    if (e < -6) {
        unsigned m = (unsigned)(a * 512.f + 0.5f);   // a/2^-9, round
        if (m >= 8) return s | 0x08;
        return s | m;
    }
    unsigned mant = (u >> 20) & 7;
    unsigned rnd  = ((u >> 19) & 1) & (((u & 0x7FFFF) != 0) | ((u >> 20) & 1));
    unsigned enc  = ((unsigned)(e + 7) << 3) | mant;
    return s | (enc + rnd);
}
__device__ __forceinline__ float dec1_fp8(unsigned b) {
    unsigned s = (b >> 7) & 1, e = (b >> 3) & 15, m = b & 7;
    float v = (e == 0) ? (float)m * 0.001953125f
                       : __uint_as_float(((e - 7 + 127) << 23) | (m << 20));
    return s ? -v : v;
}
#endif

__device__ __forceinline__ unsigned enc4_fp8(float4 v) {
#if HW_FP8
    int pk = 0;
    pk = __builtin_amdgcn_cvt_pk_fp8_f32(v.x, v.y, pk, false);
    pk = __builtin_amdgcn_cvt_pk_fp8_f32(v.z, v.w, pk, true);
    return (unsigned)pk;
#else
    return enc1_fp8(v.x) | (enc1_fp8(v.y) << 8) | (enc1_fp8(v.z) << 16) | (enc1_fp8(v.w) << 24);
#endif
}

// ---------------------------------------------------------------------------
// Convert: feat fp32 -> fp8 e4m3 table (gather source only), W -> Wt bf16 [N][K].
// ---------------------------------------------------------------------------
__global__ __launch_bounds__(256) void convert_kernel(
    const float* __restrict__ feat, const float* __restrict__ W,
    unsigned* __restrict__ feat8, unsigned short* __restrict__ Wt)
{
    const int gid = blockIdx.x * 256 + threadIdx.x;
    if (gid < FEAT4) {
        feat8[gid] = enc4_fp8(((const float4*)feat)[gid]);
    } else {
        const int t = gid - FEAT4;
        if (t < DO * DO) {
            const int n = t >> 8, k = t & 255;
            Wt[n * DO + k] = f2bf(W[k * DO + n]);   // write coalesced along k
        }
    }
}

// ---------------------------------------------------------------------------
// Aggregation from the fp8 table: row = 128 B, 16 lanes/node x 8 B (uint2),
// 16 nodes per 256-thread block. fp32 accumulate, bf16 out.
// Gather fill bytes are half of R2's bf16 version; 6.4 MB table also
// improves L2 residency.
// ---------------------------------------------------------------------------
__global__ __launch_bounds__(256) void agg_kernel(
    const unsigned* __restrict__ feat8,
    const int*      __restrict__ edges,
    unsigned short* __restrict__ aggb)
{
    const int node = blockIdx.x * 16 + (threadIdx.x >> 4);
    const int l    = threadIdx.x & 15;
    const int* e   = edges + node * DEG;

    float a[8] = {0.f, 0.f, 0.f, 0.f, 0.f, 0.f, 0.f, 0.f};
    #pragma unroll
    for (int d = 0; d < DEG; ++d) {
        const int idx = e[d];
        const uint2 pk = *(const uint2*)(feat8 + (size_t)idx * (DF / 4) + l * 2);
#if HW_FP8
        const f32x2 v0 = __builtin_amdgcn_cvt_pk_f32_fp8((int)pk.x, false);
        const f32x2 v1 = __builtin_amdgcn_cvt_pk_f32_fp8((int)pk.x, true);
        const f32x2 v2 = __builtin_amdgcn_cvt_pk_f32_fp8((int)pk.y, false);
        const f32x2 v3 = __builtin_amdgcn_cvt_pk_f32_fp8((int)pk.y, true);
        a[0] += v0[0]; a[1] += v0[1]; a[2] += v1[0]; a[3] += v1[1];
        a[4] += v2[0]; a[5] += v2[1]; a[6] += v3[0]; a[7] += v3[1];
#else
        #pragma unroll
        for (int j = 0; j < 4; ++j) a[j]     += dec1_fp8((pk.x >> (8 * j)) & 255);
        #pragma unroll
        for (int j = 0; j < 4; ++j) a[4 + j] += dec1_fp8((pk.y >> (8 * j)) & 255);
#endif
    }

    const float s = 1.0f / (float)DEG;
    u16x8 o;
    #pragma unroll
    for (int j = 0; j < 8; ++j) o[j] = f2bf(a[j] * s);
    *(u16x8*)(aggb + (size_t)node * DF + l * 8) = o;
}

// ---------------------------------------------------------------------------
// GEMM: out = relu([bf16(feat) | aggb] @ Wt^T). One block per 64 nodes,
// BN = 256 (all cols). Stage the full 64x256 A-tile once (self-features
// converted fp32->bf16 in-register; agg copied bf16) -> ONE barrier ->
// barrier-free K-loop, B-fragments straight from L2-resident Wt (128 KB).
// LDS row stride 264 bf16: 2-way max on MFMA ds_read_b128 (free, m136).
// ---------------------------------------------------------------------------
#define BM  64
#define LDA 264

__global__ __launch_bounds__(256) void gemm_kernel(
    const float*          __restrict__ feat,
    const unsigned short* __restrict__ aggb,
    const unsigned short* __restrict__ Wt,
    float*                __restrict__ out)
{
    __shared__ __align__(16) unsigned short Asw[BM * LDA];

    const int tid  = threadIdx.x;
    const int m0   = blockIdx.x * BM;
    const int wave = tid >> 6, lane = tid & 63;
    const int quad = lane >> 4, lr = lane & 15;
    const int wn   = wave * 64;

    // ---- stage A: 64 rows x (128 self + 128 agg) ----
    {
        const int row = tid >> 2;        // 0..63
        const int cb  = tid & 3;         // 4 threads per row
        int node = m0 + row;
        if (node >= NN) node = NN - 1;
        const float*          fs = feat + (size_t)node * DF;
        const unsigned short* as = aggb + (size_t)node * DF;
        #pragma unroll
        for (int p = 0; p < 4; ++p) {
            const int c8 = (cb + 4 * p) * 8;            // 0..120
            const float4 x = *(const float4*)(fs + c8);
            const float4 y = *(const float4*)(fs + c8 + 4);
            uint4 o;
            o.x = pkbf(x.x, x.y); o.y = pkbf(x.z, x.w);
            o.z = pkbf(y.x, y.y); o.w = pkbf(y.z, y.w);
            *(uint4*)(Asw + row * LDA + c8) = o;
            *(float4*)(Asw + row * LDA + DF + c8) = *(const float4*)(as + c8);
        }
    }
    __syncthreads();

    // ---- barrier-free MFMA K-loop ----
    f32x4 acc[4][4] = {};
    #pragma unroll 2
    for (int kk = 0; kk < 256; kk += 32) {
        bf16x8 af[4], bfr[4];
        #pragma unroll
        for (int i = 0; i < 4; ++i) {
            af[i]  = *(const bf16x8*)(Asw + (i * 16 + lr) * LDA + kk + quad * 8);
            bfr[i] = *(const bf16x8*)(Wt + (size_t)(wn + i * 16 + lr) * DO + kk + quad * 8);
        }
        #pragma unroll
        for (int mi = 0; mi < 4; ++mi)
            #pragma unroll
            for (int ni = 0; ni < 4; ++ni)
                acc[mi][ni] = __builtin_amdgcn_mfma_f32_16x16x32_bf16(
                    af[mi], bfr[ni], acc[mi][ni], 0, 0, 0);
    }

    // ---- epilogue: relu + guarded store. C/D: col=lane&15, row=quad*4+reg ----
    #pragma unroll
    for (int mi = 0; mi < 4; ++mi) {
        #pragma unroll
        for (int r = 0; r < 4; ++r) {
            const int row = m0 + mi * 16 + quad * 4 + r;
            if (row < NN) {
                #pragma unroll
                for (int ni = 0; ni < 4; ++ni) {
                    out[(size_t)row * DO + wn + ni * 16 + lr] =
                        fmaxf(acc[mi][ni][r], 0.f);
                }
            }
        }
    }
}

extern "C" void kernel_launch(void* const* d_in, const int* in_sizes, int n_in,
                              void* d_out, int out_size, void* d_ws, size_t ws_size,
                              hipStream_t stream)
{
    const float* feat  = (const float*)d_in[0];
    const int*   edges = (const int*)d_in[1];
    const float* W     = (const float*)d_in[2];
    float*       out   = (float*)d_out;

    unsigned short* aggb  = (unsigned short*)d_ws;              // 12.8 MB
    unsigned*       feat8 = (unsigned*)(aggb + (size_t)NN * DF);// 6.4 MB
    unsigned short* Wt    = (unsigned short*)(feat8 + (size_t)NN * DF / 4); // 128 KB

    convert_kernel<<<(FEAT4 + DO * DO + 255) / 256, 256, 0, stream>>>(feat, W, feat8, Wt);
    agg_kernel<<<NN / 16, 256, 0, stream>>>(feat8, edges, aggb);
    gemm_kernel<<<(NN + BM - 1) / BM, 256, 0, stream>>>(feat, aggb, Wt, out);
}